// Round 1
// 1242.625 us; speedup vs baseline: 1.4473x; 1.4473x over previous
//
#include <hip/hip_runtime.h>

// TernaryLinear: out[8192,11008] = x[8192,4096] @ (w*scales_grouped)[11008,4096]^T + bias
// R3: keep the bf16 pre-convert passes; replace the m97 2-barrier 128^2 GEMM with a
// 256^2 / BK=64 / 8-wave double-buffered pipeline:
//   T1 XCD swizzle, T2 LDS XOR-swizzle (both-sides via pre-swizzled global src),
//   T3 phase-split (2x32 MFMA around the stage issue), T4 counted vmcnt(8) (never 0
//   in the main loop), T5 setprio around MFMA clusters.

#define OUT_F   11008
#define IN_F    4096
#define TOKENS  8192
#define NGROUPS 32

// 256x256 tile geometry for the main GEMM
#define BM 256
#define BN 256
#define BK 64
#define KTILES (IN_F / BK)     // 64
#define NT_N   (OUT_F / BN)    // 43
#define NT_M   (TOKENS / BM)   // 32

typedef __attribute__((ext_vector_type(8))) short  short8;  // 8 bf16 = 4 VGPRs
typedef __attribute__((ext_vector_type(4))) float  f32x4;

__device__ __forceinline__ unsigned short f2bf(float f) {
    union { float f; unsigned u; } v; v.f = f;
    unsigned r = v.u + 0x7FFFu + ((v.u >> 16) & 1u);   // RNE
    return (unsigned short)(r >> 16);
}

__device__ __forceinline__ void load_lds16(const void* g, void* l) {
    // lane i's 16B -> lds_base + i*16 (wave-uniform LDS base, per-lane global addr)
    __builtin_amdgcn_global_load_lds(
        (const __attribute__((address_space(1))) unsigned int*)g,
        (__attribute__((address_space(3))) unsigned int*)l, 16, 0, 0);
}

// ---- conversion pass 1: x fp32 -> bf16 -------------------------------------
__global__ __launch_bounds__(256)
void cvt_x(const float* __restrict__ x, unsigned short* __restrict__ xb) {
    size_t i = ((size_t)blockIdx.x * 256 + threadIdx.x) * 4;
    float4 v = *(const float4*)(x + i);
    ushort4 o;
    o.x = f2bf(v.x); o.y = f2bf(v.y); o.z = f2bf(v.z); o.w = f2bf(v.w);
    *(ushort4*)(xb + i) = o;
}

// ---- conversion pass 2: W dequant (ternary * group scale) -> bf16 ----------
__global__ __launch_bounds__(256)
void cvt_w(const float* __restrict__ w, const float* __restrict__ scales,
           unsigned short* __restrict__ wb) {
    size_t i = ((size_t)blockIdx.x * 256 + threadIdx.x) * 4;
    int o = (int)(i >> 12);          // / IN_F
    int k = (int)(i & (IN_F - 1));
    float s = scales[(o << 5) + (k >> 7)];
    float4 v = *(const float4*)(w + i);
    ushort4 q;
    q.x = f2bf(v.x * s); q.y = f2bf(v.y * s);
    q.z = f2bf(v.z * s); q.w = f2bf(v.w * s);
    *(ushort4*)(wb + i) = q;
}

// ---- main GEMM: 256^2 tile, BK=64, 8 waves (2Mx4N), dbuf + counted vmcnt ----
//
// LDS layout (per buffer): A[256][64] bf16, row-major, 128B row stride, with a
// 16B-slot XOR swizzle: data for (row, slot s) lives at slot s ^ (row&7).
// global_load_lds writes linearly (base + lane*16B), so the swizzle is applied by
// permuting each lane's GLOBAL source address (rule 21: both-sides-or-neither).
//
// Per-tile schedule (tile kt reads buf=kt&1):
//   ds_read bf[4][2] + af(mh0)[4][2]   (16 x ds_read_b128, swizzled, conflict-free)
//   MFMA1: mi 0..3 x ni 0..3 x ks 0..1 = 32      [setprio 1]
//   ds_read af(mh1)[4][2]              (8 more reads)
//   lgkmcnt(0); s_barrier              <- all waves done reading buf
//   STAGE(kt+2 -> buf)                 (8 x global_load_lds, issued early)
//   MFMA2: mi 4..7 = 32                [setprio 1]   (covers stage latency)
//   vmcnt(8); s_barrier                <- tile kt+1 staged; kt+2's 8 loads stay
//                                         in flight ACROSS the barrier (T4)
__global__ __launch_bounds__(512, 2)
void gemm_bf16_256(const unsigned short* __restrict__ xb,
                   const unsigned short* __restrict__ wb,
                   const float* __restrict__ bias,
                   float* __restrict__ out) {
    __shared__ unsigned short As[2][BM * BK];   // 2 x 32 KB
    __shared__ unsigned short Bs[2][BN * BK];   // 2 x 32 KB  -> 128 KB total

    const int tid  = threadIdx.x;
    const int lane = tid & 63;
    const int wave = tid >> 6;          // 0..7
    const int wm   = wave >> 2;         // 0..1  -> row block wm*128
    const int wn   = wave & 3;          // 0..3  -> col block wn*64
    const int q    = lane >> 4;         // 0..3
    const int r    = lane & 15;

    // T1: bijective XCD swizzle (1376 = 8 * 172)
    const int cpx = (NT_N * NT_M) >> 3;              // 172
    const int bid = blockIdx.x;
    const int wg  = (bid & 7) * cpx + (bid >> 3);
    const int n0  = (wg % NT_N) * BN;
    const int m0  = (wg / NT_N) * BM;

    // staging addresses: thread tid lands its 16B at LDS byte (c*8192 + tid*16),
    // i.e. linear (row = c*64 + tid/8, slot_l = tid&7). Pre-swizzle the global
    // source so LDS slot_l holds logical slot  slot_l ^ (row&7).
    const int trow  = tid >> 3;                       // 0..63
    const int tslot = (tid & 7) ^ (trow & 7);
    const size_t gA0 = (size_t)(m0 + trow) * IN_F + tslot * 8;
    const size_t gB0 = (size_t)(n0 + trow) * IN_F + tslot * 8;
    const int ldsbase = wave << 9;                    // wave-uniform chunk base (elems)

#define STAGE(buf_, kt_)                                                      \
    do {                                                                      \
        const size_t kk_ = (size_t)(kt_) * BK;                                \
        _Pragma("unroll")                                                     \
        for (int c_ = 0; c_ < 4; ++c_) {                                      \
            load_lds16(xb + gA0 + kk_ + (size_t)c_ * 64 * IN_F,               \
                       &As[buf_][c_ * 4096 + ldsbase]);                       \
            load_lds16(wb + gB0 + kk_ + (size_t)c_ * 64 * IN_F,               \
                       &Bs[buf_][c_ * 4096 + ldsbase]);                       \
        }                                                                     \
    } while (0)

    f32x4 acc[8][4];
    const f32x4 zero = {0.0f, 0.0f, 0.0f, 0.0f};
    #pragma unroll
    for (int i = 0; i < 8; ++i)
        #pragma unroll
        for (int j = 0; j < 4; ++j)
            acc[i][j] = zero;

    float biasv[4];
    #pragma unroll
    for (int ni = 0; ni < 4; ++ni)
        biasv[ni] = bias[n0 + wn * 64 + ni * 16 + r];

    // swizzled ds_read slot offsets (elems) for k-slice 0 / 1
    const int soff0 = ((q    ) ^ (r & 7)) * 8;
    const int soff1 = ((q + 4) ^ (r & 7)) * 8;

    // prologue: fill both buffers; wait for tile 0 only (tile 1 stays in flight)
    STAGE(0, 0);
    STAGE(1, 1);
    asm volatile("s_waitcnt vmcnt(8)" ::: "memory");
    __builtin_amdgcn_s_barrier();
    __builtin_amdgcn_sched_barrier(0);

    #pragma unroll 2
    for (int kt = 0; kt < KTILES; ++kt) {
        const int buf = kt & 1;
        const unsigned short* Abase = &As[buf][(wm * 128 + r) * 64];
        const unsigned short* Bbase = &Bs[buf][(wn * 64  + r) * 64];

        short8 af[4][2], bf[4][2];
        #pragma unroll
        for (int ni = 0; ni < 4; ++ni) {
            bf[ni][0] = *(const short8*)(Bbase + ni * 1024 + soff0);
            bf[ni][1] = *(const short8*)(Bbase + ni * 1024 + soff1);
        }
        #pragma unroll
        for (int mi = 0; mi < 4; ++mi) {
            af[mi][0] = *(const short8*)(Abase + mi * 1024 + soff0);
            af[mi][1] = *(const short8*)(Abase + mi * 1024 + soff1);
        }

        __builtin_amdgcn_s_setprio(1);
        #pragma unroll
        for (int mi = 0; mi < 4; ++mi)
            #pragma unroll
            for (int ni = 0; ni < 4; ++ni) {
                acc[mi][ni] = __builtin_amdgcn_mfma_f32_16x16x32_bf16(
                    af[mi][0], bf[ni][0], acc[mi][ni], 0, 0, 0);
                acc[mi][ni] = __builtin_amdgcn_mfma_f32_16x16x32_bf16(
                    af[mi][1], bf[ni][1], acc[mi][ni], 0, 0, 0);
            }
        __builtin_amdgcn_s_setprio(0);

        // reload A fragments for the second m-half (rows +64)
        #pragma unroll
        for (int mi = 0; mi < 4; ++mi) {
            af[mi][0] = *(const short8*)(Abase + 4096 + mi * 1024 + soff0);
            af[mi][1] = *(const short8*)(Abase + 4096 + mi * 1024 + soff1);
        }

        asm volatile("s_waitcnt lgkmcnt(0)" ::: "memory");   // all reads of buf done
        __builtin_amdgcn_s_barrier();                        // -> buf is dead, safe to overwrite
        __builtin_amdgcn_sched_barrier(0);

        if (kt < KTILES - 2)
            STAGE(buf, kt + 2);                              // issue early; lands ~1.5 tiles later
        __builtin_amdgcn_sched_barrier(0);                   // keep MFMA2 below the stage issue

        __builtin_amdgcn_s_setprio(1);
        #pragma unroll
        for (int mi = 0; mi < 4; ++mi)
            #pragma unroll
            for (int ni = 0; ni < 4; ++ni) {
                acc[mi + 4][ni] = __builtin_amdgcn_mfma_f32_16x16x32_bf16(
                    af[mi][0], bf[ni][0], acc[mi + 4][ni], 0, 0, 0);
                acc[mi + 4][ni] = __builtin_amdgcn_mfma_f32_16x16x32_bf16(
                    af[mi][1], bf[ni][1], acc[mi + 4][ni], 0, 0, 0);
            }
        __builtin_amdgcn_s_setprio(0);

        // T4: counted drain — tile kt+1 must be landed; tile kt+2's 8 loads may
        // remain in flight across the barrier. Never vmcnt(0) mid-loop.
        if (kt < KTILES - 2) {
            asm volatile("s_waitcnt vmcnt(8)" ::: "memory");
        } else {
            asm volatile("s_waitcnt vmcnt(0)" ::: "memory");
        }
        __builtin_amdgcn_s_barrier();
        __builtin_amdgcn_sched_barrier(0);
    }
#undef STAGE

    // epilogue: C/D layout col=lane&15, row=q*4+e (verified in R1)
    #pragma unroll
    for (int mi = 0; mi < 8; ++mi) {
        const int row0 = m0 + wm * 128 + mi * 16 + q * 4;
        #pragma unroll
        for (int ni = 0; ni < 4; ++ni) {
            const int col = n0 + wn * 64 + ni * 16 + r;
            const float bv = biasv[ni];
            #pragma unroll
            for (int e = 0; e < 4; ++e)
                out[(size_t)(row0 + e) * OUT_F + col] = acc[mi][ni][e] + bv;
        }
    }
}

// ---- fallback (round-1 fused kernel) if workspace too small ----------------
#define LDS_STRIDE 40
__global__ __launch_bounds__(256, 2)
void ternary_gemm_fused(const float* __restrict__ x,
                        const float* __restrict__ w,
                        const float* __restrict__ scales,
                        const float* __restrict__ bias,
                        float* __restrict__ out) {
    __shared__ unsigned short As[128 * LDS_STRIDE];
    __shared__ unsigned short Bs[128 * LDS_STRIDE];

    const int tid  = threadIdx.x;
    const int lane = tid & 63;
    const int wave = tid >> 6;
    const int wm   = (wave & 1) * 64;
    const int wn   = (wave >> 1) * 64;
    const int q    = lane >> 4;
    const int r    = lane & 15;
    const int n0 = blockIdx.x * 128;
    const int m0 = blockIdx.y * 128;
    const int srow = tid >> 3;
    const int scol = (tid & 7) * 4;

    f32x4 acc[4][4];
    const f32x4 zero = {0.0f, 0.0f, 0.0f, 0.0f};
    #pragma unroll
    for (int i = 0; i < 4; ++i)
        #pragma unroll
        for (int j = 0; j < 4; ++j)
            acc[i][j] = zero;

    float biasv[4];
    #pragma unroll
    for (int ni = 0; ni < 4; ++ni)
        biasv[ni] = bias[n0 + wn + ni * 16 + r];

    for (int kt = 0; kt < IN_F / 32; ++kt) {
        const int k0 = kt * 32;
        const int g  = k0 >> 7;
        float4 a4[4], b4[4];
        float  sc[4];
        #pragma unroll
        for (int s = 0; s < 4; ++s) {
            const int row = s * 32 + srow;
            a4[s] = *(const float4*)(x + (size_t)(m0 + row) * IN_F + k0 + scol);
            b4[s] = *(const float4*)(w + (size_t)(n0 + row) * IN_F + k0 + scol);
            sc[s] = scales[(n0 + row) * NGROUPS + g];
        }
        __syncthreads();
        #pragma unroll
        for (int s = 0; s < 4; ++s) {
            const int row = s * 32 + srow;
            ushort4 av, bv;
            av.x = f2bf(a4[s].x);          av.y = f2bf(a4[s].y);
            av.z = f2bf(a4[s].z);          av.w = f2bf(a4[s].w);
            bv.x = f2bf(b4[s].x * sc[s]);  bv.y = f2bf(b4[s].y * sc[s]);
            bv.z = f2bf(b4[s].z * sc[s]);  bv.w = f2bf(b4[s].w * sc[s]);
            *(ushort4*)(As + row * LDS_STRIDE + scol) = av;
            *(ushort4*)(Bs + row * LDS_STRIDE + scol) = bv;
        }
        __syncthreads();
        short8 af[4], bf[4];
        #pragma unroll
        for (int mi = 0; mi < 4; ++mi)
            af[mi] = *(const short8*)(As + (wm + mi * 16 + r) * LDS_STRIDE + q * 8);
        #pragma unroll
        for (int ni = 0; ni < 4; ++ni)
            bf[ni] = *(const short8*)(Bs + (wn + ni * 16 + r) * LDS_STRIDE + q * 8);
        #pragma unroll
        for (int mi = 0; mi < 4; ++mi)
            #pragma unroll
            for (int ni = 0; ni < 4; ++ni)
                acc[mi][ni] = __builtin_amdgcn_mfma_f32_16x16x32_bf16(
                    af[mi], bf[ni], acc[mi][ni], 0, 0, 0);
    }
    #pragma unroll
    for (int mi = 0; mi < 4; ++mi) {
        const int row0 = m0 + wm + mi * 16 + q * 4;
        #pragma unroll
        for (int ni = 0; ni < 4; ++ni) {
            const int col = n0 + wn + ni * 16 + r;
            const float bv = biasv[ni];
            #pragma unroll
            for (int e = 0; e < 4; ++e)
                out[(size_t)(row0 + e) * OUT_F + col] = acc[mi][ni][e] + bv;
        }
    }
}

extern "C" void kernel_launch(void* const* d_in, const int* in_sizes, int n_in,
                              void* d_out, int out_size, void* d_ws, size_t ws_size,
                              hipStream_t stream) {
    const float* x      = (const float*)d_in[0];
    const float* w      = (const float*)d_in[1];
    const float* scales = (const float*)d_in[2];
    const float* bias   = (const float*)d_in[3];
    float* out          = (float*)d_out;

    const size_t xb_elems = (size_t)TOKENS * IN_F;           // 33.5M
    const size_t wb_elems = (size_t)OUT_F * IN_F;            // 45.1M
    const size_t need = (xb_elems + wb_elems) * sizeof(unsigned short);  // ~157 MB

    if (ws_size >= need) {
        unsigned short* xb = (unsigned short*)d_ws;
        unsigned short* wb = xb + xb_elems;
        cvt_x<<<(int)(xb_elems / 1024), 256, 0, stream>>>(x, xb);
        cvt_w<<<(int)(wb_elems / 1024), 256, 0, stream>>>(w, scales, wb);
        gemm_bf16_256<<<dim3(NT_N * NT_M), dim3(512), 0, stream>>>(xb, wb, bias, out);
    } else {
        dim3 grid(OUT_F / 128, TOKENS / 128);
        ternary_gemm_fused<<<grid, 128 * 2, 0, stream>>>(x, w, scales, bias, out);
    }
}